// Round 8
// baseline (1078.301 us; speedup 1.0000x reference)
//
#include <hip/hip_runtime.h>
#include <math.h>

#define N_NODES 50000
#define N_PAD   50048            // padded rows for 128-row GEMM tiles
#define E_EDGES 1600000
#define ETOT    (E_EDGES + N_NODES)
#define EPAD    (E_EDGES + 8 * N_NODES)   // CSR rows padded to multiple of 8
#define IN_DIM  300
#define KP1     320              // IN_DIM padded to mult of 32
#define HID     256
#define HEADS   8
#define OC      32
#define LAYERS  4
#define BSAMP   1024
#define NEG_SLOPE 0.2f
#define NS1     (N_NODES + 1)    // s_src stride (sentinel slot at index N_NODES)

// XCD-bucketed CSR build
#define NB     8                 // buckets = XCDs (also heads in agg)
#define NPB    6250              // nodes per bucket (50000/8)
#define BCAP   262144            // per-bucket partition capacity (mean 206k)
#define NBLK_P 512               // partition blocks
#define NBLK_S 196               // scan blocks (50000/256 rounded up)
#define NBLK_B 2048              // bucket count/fill blocks (256 per bucket)
#define NAGG   1536              // 6 blocks/CU exactly resident; head = blk&7
#define NW2    ((NAGG / NB) * 4 * 2)      // pair stride (768 waves/head * 2)

typedef unsigned long long ull;
typedef unsigned short u16;
typedef _Float16 half8 __attribute__((ext_vector_type(8)));
typedef float f32x4 __attribute__((ext_vector_type(4)));

#define GLDS16(g, l) __builtin_amdgcn_global_load_lds( \
    (const __attribute__((address_space(1))) void*)(g), \
    (__attribute__((address_space(3))) void*)(l), 16, 0, 0)

// ---------------------------------------------------------------- CSR build
// Two-pass block-local radix partition by tgt bucket. No global atomics.

__global__ __launch_bounds__(256) void part_count_kernel(const int* __restrict__ tgt,
                                                         int* __restrict__ gcount) {
    __shared__ int cnt[NB];
    if (threadIdx.x < NB) cnt[threadIdx.x] = 0;
    __syncthreads();
    const int chunk = (ETOT + NBLK_P - 1) / NBLK_P;
    int beg = blockIdx.x * chunk;
    int end = min(beg + chunk, ETOT);
    for (int e = beg + threadIdx.x; e < end; e += 256) {
        int t_ = (e < E_EDGES) ? tgt[e] : (e - E_EDGES);
        atomicAdd(&cnt[t_ / NPB], 1);
    }
    __syncthreads();
    if (threadIdx.x < NB) gcount[blockIdx.x * NB + threadIdx.x] = cnt[threadIdx.x];
}

// parallel scan over NBLK_P block-counts x NB buckets (1 block, 512 threads)
__global__ __launch_bounds__(512) void part_scan_kernel(const int* __restrict__ gcount,
                                                        int* __restrict__ goff,
                                                        int* __restrict__ bcnt) {
    __shared__ int arr[NBLK_P][NB];
    int k = threadIdx.x;
    int4 a = ((const int4*)gcount)[k * 2];
    int4 b = ((const int4*)gcount)[k * 2 + 1];
    int own[NB] = {a.x, a.y, a.z, a.w, b.x, b.y, b.z, b.w};
    #pragma unroll
    for (int j = 0; j < NB; j++) arr[k][j] = own[j];
    __syncthreads();
    for (int off = 1; off < NBLK_P; off <<= 1) {
        int tmp[NB];
        #pragma unroll
        for (int j = 0; j < NB; j++) tmp[j] = (k >= off) ? arr[k - off][j] : 0;
        __syncthreads();
        #pragma unroll
        for (int j = 0; j < NB; j++) arr[k][j] += tmp[j];
        __syncthreads();
    }
    int ex[NB];
    #pragma unroll
    for (int j = 0; j < NB; j++) ex[j] = arr[k][j] - own[j];   // exclusive
    ((int4*)goff)[k * 2]     = make_int4(ex[0], ex[1], ex[2], ex[3]);
    ((int4*)goff)[k * 2 + 1] = make_int4(ex[4], ex[5], ex[6], ex[7]);
    if (k == NBLK_P - 1) {
        #pragma unroll
        for (int j = 0; j < NB; j++) bcnt[j] = arr[k][j];
    }
}

__global__ __launch_bounds__(256) void part_scatter_kernel(const int* __restrict__ src,
                                                           const int* __restrict__ tgt,
                                                           const int* __restrict__ goff,
                                                           ull* __restrict__ bpart) {
    __shared__ int cur[NB];
    if (threadIdx.x < NB) cur[threadIdx.x] = goff[blockIdx.x * NB + threadIdx.x];
    __syncthreads();
    const int chunk = (ETOT + NBLK_P - 1) / NBLK_P;
    int beg = blockIdx.x * chunk;
    int end = min(beg + chunk, ETOT);
    for (int e = beg + threadIdx.x; e < end; e += 256) {
        int s_, t_;
        if (e < E_EDGES) { s_ = src[e]; t_ = tgt[e]; }
        else             { s_ = t_ = e - E_EDGES; }
        int b = t_ / NPB;
        int pos = atomicAdd(&cur[b], 1);
        bpart[(size_t)b * BCAP + pos] = ((ull)(unsigned)t_ << 32) | (unsigned)s_;
    }
}

// per-bucket degree count (blockIdx%8 = bucket -> XCD-local counts lines)
__global__ __launch_bounds__(256) void count_edges_kernel(const ull* __restrict__ bpart,
                                                          const int* __restrict__ bcnt,
                                                          int* counts) {
    int b = blockIdx.x & (NB - 1);
    int ib = blockIdx.x >> 3;
    int nblk = gridDim.x >> 3;
    int nb = bcnt[b];
    const ull* bp = bpart + (size_t)b * BCAP;
    for (int i = ib * 256 + threadIdx.x; i < nb; i += nblk * 256)
        atomicAdd(&counts[(int)(bp[i] >> 32)], 1);
}

// ---------------- parallel scan of padded counts (3 tiny kernels) ----------
__global__ __launch_bounds__(256) void scan1_kernel(const int* __restrict__ counts,
                                                    int* __restrict__ row_ptr,
                                                    int* __restrict__ bsum) {
    __shared__ int sums[256];
    int t = threadIdx.x;
    int i = blockIdx.x * 256 + t;
    int c = (i < N_NODES) ? ((counts[i] + 7) & ~7) : 0;
    sums[t] = c;
    __syncthreads();
    for (int off = 1; off < 256; off <<= 1) {
        int a = sums[t];
        int u = (t >= off) ? sums[t - off] : 0;
        __syncthreads();
        sums[t] = a + u;
        __syncthreads();
    }
    if (i < N_NODES) row_ptr[i] = sums[t] - c;   // local exclusive
    if (t == 255) bsum[blockIdx.x] = sums[255];
}

__global__ __launch_bounds__(256) void scan2_kernel(const int* __restrict__ bsum,
                                                    int* __restrict__ boff,
                                                    int* __restrict__ row_ptr) {
    __shared__ int sums[256];
    int t = threadIdx.x;
    int b = (t < NBLK_S) ? bsum[t] : 0;
    sums[t] = b;
    __syncthreads();
    for (int off = 1; off < 256; off <<= 1) {
        int a = sums[t];
        int u = (t >= off) ? sums[t - off] : 0;
        __syncthreads();
        sums[t] = a + u;
        __syncthreads();
    }
    if (t < NBLK_S) boff[t] = sums[t] - b;
    if (t == 255) row_ptr[N_NODES] = sums[255];
}

__global__ __launch_bounds__(256) void scan3_kernel(int* __restrict__ row_ptr,
                                                    const int* __restrict__ boff,
                                                    int* __restrict__ cursor) {
    int i = blockIdx.x * 256 + threadIdx.x;
    if (i >= N_NODES) return;
    int v = row_ptr[i] + boff[blockIdx.x];
    row_ptr[i] = v;
    cursor[i]  = v;
}

// per-bucket scatter into col (cursor + col lines XCD-local); col is u16
__global__ __launch_bounds__(256) void fill_edges_kernel(const ull* __restrict__ bpart,
                                                         const int* __restrict__ bcnt,
                                                         int* cursor, u16* __restrict__ col) {
    int b = blockIdx.x & (NB - 1);
    int ib = blockIdx.x >> 3;
    int nblk = gridDim.x >> 3;
    int nb = bcnt[b];
    const ull* bp = bpart + (size_t)b * BCAP;
    for (int i = ib * 256 + threadIdx.x; i < nb; i += nblk * 256) {
        ull pk = bp[i];
        int t_ = (int)(pk >> 32);
        int s_ = (int)pk;
        int pos = atomicAdd(&cursor[t_], 1);
        col[pos] = (u16)s_;
    }
}

// fill pad slots with SENTINEL node id (s_src[sentinel] = -1e30 -> ex == 0)
__global__ __launch_bounds__(256) void pad_edges_kernel(const int* __restrict__ cursor,
                                                        const int* __restrict__ row_ptr,
                                                        u16* __restrict__ col) {
    int i = blockIdx.x * 256 + threadIdx.x;
    if (i >= N_NODES) return;
    int e = cursor[i];            // true end after fill
    int pe = row_ptr[i + 1];      // padded end
    for (; e < pe; e++) col[e] = (u16)N_NODES;
}

// ---------------------------------------------------------------- fp32 -> fp16 casts

__global__ __launch_bounds__(256) void cast_x_kernel(const float* __restrict__ x, _Float16* __restrict__ xh) {
    int i = blockIdx.x * 256 + threadIdx.x;          // over 50000*40 half8s
    if (i >= N_NODES * (KP1 / 8)) return;
    int r = i / (KP1 / 8), c8 = i % (KP1 / 8);
    half8 o;
    const float4* xr = (const float4*)(x + (size_t)r * IN_DIM);
    if (c8 < 37) {
        float4 u = xr[c8 * 2], v = xr[c8 * 2 + 1];
        o[0] = (_Float16)u.x; o[1] = (_Float16)u.y; o[2] = (_Float16)u.z; o[3] = (_Float16)u.w;
        o[4] = (_Float16)v.x; o[5] = (_Float16)v.y; o[6] = (_Float16)v.z; o[7] = (_Float16)v.w;
    } else if (c8 == 37) {
        float4 u = xr[74];
        o[0] = (_Float16)u.x; o[1] = (_Float16)u.y; o[2] = (_Float16)u.z; o[3] = (_Float16)u.w;
        o[4] = o[5] = o[6] = o[7] = (_Float16)0.f;
    } else {
        #pragma unroll
        for (int j = 0; j < 8; j++) o[j] = (_Float16)0.f;
    }
    ((half8*)xh)[i] = o;
}

__global__ __launch_bounds__(256) void cast_w1_kernel(const float* __restrict__ W, _Float16* __restrict__ Wt) {
    int i = blockIdx.x * 256 + threadIdx.x;
    if (i >= HID * KP1) return;
    int n = i / KP1, k = i % KP1;
    float v = (k < IN_DIM) ? W[(size_t)k * HID + n] : 0.f;
    Wt[i] = (_Float16)v;
}

__global__ __launch_bounds__(256) void cast_wc_kernel(const float* __restrict__ W, _Float16* __restrict__ Wt) {
    int i = blockIdx.x * 256 + threadIdx.x;
    if (i >= LAYERS * HID * HID) return;
    int l = i / (HID * HID);
    int r = i % (HID * HID);
    int n = r / HID, k = r % HID;
    Wt[i] = (_Float16)W[(size_t)l * HID * HID + (size_t)k * HID + n];
}

// ---------------------------------------------------------------- fp16 MFMA GEMM
// headmajor=1 writes C as [head][node][32] (stride N_NODES rows per head slice)
__global__ __launch_bounds__(256) void gemm_mfma_kernel(const _Float16* __restrict__ A,
                                                        const _Float16* __restrict__ Wt,
                                                        const float* __restrict__ bias,
                                                        _Float16* __restrict__ C,
                                                        int M, int Kp, int addbias,
                                                        int headmajor) {
    __shared__ _Float16 As[128][32];
    __shared__ _Float16 Bs[128][32];
    const int tid = threadIdx.x;
    const int m0 = blockIdx.x * 128;
    const int n0 = blockIdx.y * 128;
    const int w = tid >> 6, lane = tid & 63;
    const int wm = (w & 1) * 64, wn = (w >> 1) * 64;
    const int quad = lane >> 4, m16 = lane & 15;

    f32x4 acc[4][4];
    #pragma unroll
    for (int i = 0; i < 4; i++)
        #pragma unroll
        for (int j = 0; j < 4; j++)
            acc[i][j] = (f32x4){0.f, 0.f, 0.f, 0.f};

    char* lA = (char*)&As[0][0] + w * 1024;   // wave-uniform LDS bases
    char* lB = (char*)&Bs[0][0] + w * 1024;

    for (int k0 = 0; k0 < Kp; k0 += 32) {
        #pragma unroll
        for (int i = 0; i < 2; i++) {
            int seg = tid + i * 256;
            int row = seg >> 2, off = seg & 3;
            GLDS16(&A[(size_t)(m0 + row) * Kp + k0 + off * 8], lA + i * 4096);
            GLDS16(&Wt[(size_t)(n0 + row) * Kp + k0 + off * 8], lB + i * 4096);
        }
        __syncthreads();

        half8 af[4], bf[4];
        #pragma unroll
        for (int i = 0; i < 4; i++) {
            af[i] = *(const half8*)&As[wm + i * 16 + m16][quad * 8];
            bf[i] = *(const half8*)&Bs[wn + i * 16 + m16][quad * 8];
        }
        #pragma unroll
        for (int mi = 0; mi < 4; mi++)
            #pragma unroll
            for (int ni = 0; ni < 4; ni++)
                acc[mi][ni] = __builtin_amdgcn_mfma_f32_16x16x32_f16(af[mi], bf[ni], acc[mi][ni], 0, 0, 0);
        __syncthreads();
    }

    #pragma unroll
    for (int mi = 0; mi < 4; mi++) {
        #pragma unroll
        for (int r = 0; r < 4; r++) {
            int row = m0 + wm + mi * 16 + quad * 4 + r;
            if (row < M) {
                #pragma unroll
                for (int ni = 0; ni < 4; ni++) {
                    int colg = n0 + wn + ni * 16 + m16;
                    float v = acc[mi][ni][r];
                    if (addbias) v += bias[colg];
                    if (headmajor) {
                        int hd = colg >> 5, oc = colg & 31;
                        C[((size_t)hd * N_NODES + row) * 32 + oc] = (_Float16)v;
                    } else {
                        C[(size_t)row * HID + colg] = (_Float16)v;
                    }
                }
            }
        }
    }
}

// ---------------------------------------------------------------- attention scores
// hw is head-major [head][node][32]; s_dst [head][node]; s_src [head][N+1]
// (slot N is the sentinel = -1e30 so padded edges contribute ex = 0).
__global__ __launch_bounds__(256) void score_kernel(const _Float16* __restrict__ hw,
                                                    const float* __restrict__ att_dst,
                                                    const float* __restrict__ att_src,
                                                    float* __restrict__ s_dst,
                                                    float* __restrict__ s_src) {
    if (blockIdx.x == 0 && threadIdx.x < HEADS)
        s_src[(size_t)threadIdx.x * NS1 + N_NODES] = -1e30f;
    int wv = threadIdx.x >> 6, lane = threadIdx.x & 63;
    int nd = lane >> 3, hd = lane & 7;
    float4 ad[8], as4[8];
    const float4* A4d = (const float4*)att_dst;
    const float4* A4s = (const float4*)att_src;
    #pragma unroll
    for (int j = 0; j < 8; j++) { ad[j] = A4d[hd * 8 + j]; as4[j] = A4s[hd * 8 + j]; }
    const half8* hw8 = (const half8*)hw;
    int nwaves = gridDim.x * 4;
    for (int g = blockIdx.x * 4 + wv; g < N_NODES / 8; g += nwaves) {
        int node = g * 8 + nd;
        float sd = 0.f, ss = 0.f;
        #pragma unroll
        for (int k = 0; k < 4; k++) {
            half8 v = hw8[((size_t)hd * N_NODES + node) * 4 + k];
            #pragma unroll
            for (int i = 0; i < 8; i++) {
                float f = (float)v[i];
                int q = k * 8 + i;
                sd += f * ((const float*)&ad[q >> 2])[q & 3];
                ss += f * ((const float*)&as4[q >> 2])[q & 3];
            }
        }
        s_dst[(size_t)hd * N_NODES + node] = sd;
        s_src[(size_t)hd * NS1 + node] = ss;
    }
}

// ---------------------------------------------------------------- aggregation
// R16: R15 lane layout (nh node-half, es 8 slots, cl 4x16B) + pair-level
// software pipeline: A-issue(pair i+1) -> registers, phaseC(pair i) from LDS
// buf CUR, A-write(pair i+1) -> buf NXT (exp+pack after compute: both L2
// round-trips of phase A hide under pair i's compute). LDS entries packed
// {ex,snb} as one ull -> single ds_read_b64 per phase-C group. Zero-pad is
// merged into the masked A-write (sentinel -> ex=0). Buffers addressed by
// macro literals so the compiler can disambiguate LDS aliasing.
__global__ __launch_bounds__(256, 6) void agg_kernel(const int* __restrict__ row_ptr,
                                                     const u16* __restrict__ col,
                                                     const float* __restrict__ s_dst,
                                                     const float* __restrict__ s_src,
                                                     const _Float16* __restrict__ hw,
                                                     const float* __restrict__ bias,
                                                     _Float16* __restrict__ h_out) {
    __shared__ ull pkL[4][2][2][128];          // [wave][buf][node-region][slot]

    const int wv   = threadIdx.x >> 6;
    const int lane = threadIdx.x & 63;
    const int head = blockIdx.x & (NB - 1);    // head == XCD
    const int ib   = blockIdx.x >> 3;
    const int nh   = lane >> 5;                // node half
    const int es   = (lane >> 2) & 7;          // edge slot 0..7
    const int cl   = lane & 3;                 // channel lane: 8 ch (16B)
    const int wid  = ib * 4 + wv;              // 0..(NAGG/NB*4)-1

    const float* sdh = s_dst + (size_t)head * N_NODES;
    const float* ssh = s_src + (size_t)head * NS1;
    const char*  hwh = (const char*)(hw + (size_t)head * N_NODES * 32);
    const unsigned vcl = (unsigned)(cl * 16);

    float dsum, a0, a1, a2, a3, a4, a5, a6, a7;

    // pack + masked write of one slot (sentinel sn -> ex = 0; merged zero-pad)
    auto wr = [&](ull* pkd, int slot, int mx_, float sdv, float ss, int sn) {
        if (slot < mx_) {
            float a = sdv + ss;
            a = fmaxf(a, NEG_SLOPE * a);
            float ex = __expf(a);
            pkd[slot] = ((ull)__float_as_uint(ex) << 32) | (unsigned)(sn << 6);
        }
    };

    // accumulate ngrp groups from this lane's packed region
    auto phaseC = [&](const ull* pkw, int ngrp) {
        ull p0 = pkw[es];
        ull p1 = (ngrp > 1) ? pkw[8 + es] : 0;
        half8 v0 = *(const half8*)(hwh + ((unsigned)(p0 & 0xffffffffu) | vcl));
        for (int g = 0; g < ngrp; g++) {
            ull p2 = (g + 2 < ngrp) ? pkw[(g + 2) * 8 + es] : 0;
            half8 vn = *(const half8*)(hwh + ((unsigned)(p1 & 0xffffffffu) | vcl));
            float e = __uint_as_float((unsigned)(p0 >> 32));
            dsum += e;
            a0 += e * (float)v0[0];
            a1 += e * (float)v0[1];
            a2 += e * (float)v0[2];
            a3 += e * (float)v0[3];
            a4 += e * (float)v0[4];
            a5 += e * (float)v0[5];
            a6 += e * (float)v0[6];
            a7 += e * (float)v0[7];
            p0 = p1; p1 = p2; v0 = vn;
        }
    };

    // reduce + epilogue for pair base tbp
    auto finish = [&](int tbp) {
        #pragma unroll
        for (int off = 4; off <= 16; off <<= 1) {
            dsum += __shfl_xor(dsum, off);
            a0 += __shfl_xor(a0, off);
            a1 += __shfl_xor(a1, off);
            a2 += __shfl_xor(a2, off);
            a3 += __shfl_xor(a3, off);
            a4 += __shfl_xor(a4, off);
            a5 += __shfl_xor(a5, off);
            a6 += __shfl_xor(a6, off);
            a7 += __shfl_xor(a7, off);
        }
        if (es == 0) {
            const float* bpt = bias + head * 32 + cl * 8;
            float inv = 1.f / (dsum + 1e-16f);
            float o[8] = {a0 * inv + bpt[0], a1 * inv + bpt[1],
                          a2 * inv + bpt[2], a3 * inv + bpt[3],
                          a4 * inv + bpt[4], a5 * inv + bpt[5],
                          a6 * inv + bpt[6], a7 * inv + bpt[7]};
            half8 ov;
            #pragma unroll
            for (int i = 0; i < 8; i++) {
                float v = (o[i] > 0.f) ? o[i] : (__expf(o[i]) - 1.f);
                ov[i] = (_Float16)v;
            }
            *(half8*)(h_out + (size_t)(tbp + nh) * HID + head * 32 + cl * 8) = ov;
        }
    };

    // rotating pair state
    int cbig, cmx, cr0, cr1, cpd0, cpd1;
    float csd0, csd1;
    int tb = wid * 2;

    // ---- prologue: stage pair tb into buf 0 (no overlap needed) ----
    {
        cr0 = row_ptr[tb]; cr1 = row_ptr[tb + 1];
        int r2 = row_ptr[tb + 2];
        cpd0 = cr1 - cr0; cpd1 = r2 - cr1;
        csd0 = sdh[tb]; csd1 = sdh[tb + 1];
        cbig = (cpd0 > 128) || (cpd1 > 128);
        cmx = max(cpd0, cpd1);
        if (!cbig) {
            int sA = N_NODES, sB = N_NODES, sC = N_NODES, sD = N_NODES;
            if (lane < cpd0)      sA = (int)col[cr0 + lane];
            if (lane + 64 < cpd0) sB = (int)col[cr0 + lane + 64];
            if (lane < cpd1)      sC = (int)col[cr1 + lane];
            if (lane + 64 < cpd1) sD = (int)col[cr1 + lane + 64];
            float eA = ssh[(unsigned)sA], eB = ssh[(unsigned)sB];
            float eC = ssh[(unsigned)sC], eD = ssh[(unsigned)sD];
            wr(&pkL[wv][0][0][0], lane,      cmx, csd0, eA, sA);
            wr(&pkL[wv][0][0][0], lane + 64, cmx, csd0, eB, sB);
            wr(&pkL[wv][0][1][0], lane,      cmx, csd1, eC, sC);
            wr(&pkL[wv][0][1][0], lane + 64, cmx, csd1, eD, sD);
        }
    }

#define AGG_PROC(CUR, NXT)                                                     \
    do {                                                                       \
        int tn = tb + NW2;                                                     \
        bool hn = tn < N_NODES;                                                \
        int nbig = 0, nmx = 0, nr0 = 0, nr1 = 0, npd0 = 0, npd1 = 0;           \
        float nsd0 = 0.f, nsd1 = 0.f;                                          \
        int sA = N_NODES, sB = N_NODES, sC = N_NODES, sD = N_NODES;            \
        if (hn) {                                                              \
            nr0 = row_ptr[tn]; nr1 = row_ptr[tn + 1];                          \
            int r2n = row_ptr[tn + 2];                                         \
            npd0 = nr1 - nr0; npd1 = r2n - nr1;                                \
            nsd0 = sdh[tn]; nsd1 = sdh[tn + 1];                                \
            nbig = (npd0 > 128) || (npd1 > 128);                               \
            nmx = max(npd0, npd1);                                             \
            if (!nbig) {                                                       \
                if (lane < npd0)      sA = (int)col[nr0 + lane];               \
                if (lane + 64 < npd0) sB = (int)col[nr0 + lane + 64];          \
                if (lane < npd1)      sC = (int)col[nr1 + lane];               \
                if (lane + 64 < npd1) sD = (int)col[nr1 + lane + 64];          \
            }                                                                  \
        }                                                                      \
        float eA = ssh[(unsigned)sA], eB = ssh[(unsigned)sB];                  \
        float eC = ssh[(unsigned)sC], eD = ssh[(unsigned)sD];                  \
        dsum = 0.f;                                                            \
        a0 = a1 = a2 = a3 = a4 = a5 = a6 = a7 = 0.f;                           \
        if (!cbig) {                                                           \
            phaseC(&pkL[wv][CUR][nh][0], cmx >> 3);                            \
        } else {                                                               \
            for (int slot = lane; slot < 128; slot += 64) {                    \
                pkL[wv][CUR][0][slot] = 0ull;                                  \
                pkL[wv][CUR][1][slot] = 0ull;                                  \
            }                                                                  \
            for (int s = 0; s < 2; s++) {                                      \
                int rs = s ? cr1 : cr0;                                        \
                int pds = s ? cpd1 : cpd0;                                     \
                float sdvs = s ? csd1 : csd0;                                  \
                for (int c0 = 0; c0 < pds; c0 += 128) {                        \
                    int csz = min(pds - c0, 128);                              \
                    for (int b = 0; b < csz; b += 64) {                        \
                        int slot = b + lane;                                   \
                        if (slot < csz) {                                      \
                            int sn = (int)col[rs + c0 + slot];                 \
                            float a = sdvs + ssh[(unsigned)sn];                \
                            a = fmaxf(a, NEG_SLOPE * a);                       \
                            pkL[wv][CUR][s][slot] =                            \
                                ((ull)__float_as_uint(__expf(a)) << 32) |      \
                                (unsigned)(sn << 6);                           \
                        }                                                      \
                    }                                                          \
                    phaseC(&pkL[wv][CUR][nh][0], csz >> 3);                    \
                }                                                              \
                for (int slot = lane; slot < 128; slot += 64)                  \
                    pkL[wv][CUR][s][slot] = 0ull;                              \
            }                                                                  \
        }                                                                      \
        if (hn && !nbig) {                                                     \
            wr(&pkL[wv][NXT][0][0], lane,      nmx, nsd0, eA, sA);             \
            wr(&pkL[wv][NXT][0][0], lane + 64, nmx, nsd0, eB, sB);             \
            wr(&pkL[wv][NXT][1][0], lane,      nmx, nsd1, eC, sC);             \
            wr(&pkL[wv][NXT][1][0], lane + 64, nmx, nsd1, eD, sD);             \
        }                                                                      \
        finish(tb);                                                            \
        cbig = nbig; cmx = nmx; cr0 = nr0; cr1 = nr1;                          \
        cpd0 = npd0; cpd1 = npd1; csd0 = nsd0; csd1 = nsd1;                    \
    } while (0)

    for (;;) {
        AGG_PROC(0, 1);
        tb += NW2;
        if (tb >= N_NODES) break;
        AGG_PROC(1, 0);
        tb += NW2;
        if (tb >= N_NODES) break;
    }
#undef AGG_PROC
}

// ---------------------------------------------------------------- head
__global__ __launch_bounds__(256) void head_kernel(const _Float16* __restrict__ h,
                                                   const int* __restrict__ target_mask,
                                                   const float* __restrict__ W,
                                                   const float* __restrict__ b,
                                                   float* __restrict__ out) {
    int s = blockIdx.x;
    int t = threadIdx.x;
    int n0 = target_mask[s * 2 + 0];
    int n1 = target_mask[s * 2 + 1];
    float f0 = (float)h[(size_t)n0 * HID + t];
    float f1 = (float)h[(size_t)n1 * HID + t];
    float a0 = f0 * W[t * 3 + 0] + f1 * W[(t + 256) * 3 + 0];
    float a1 = f0 * W[t * 3 + 1] + f1 * W[(t + 256) * 3 + 1];
    float a2 = f0 * W[t * 3 + 2] + f1 * W[(t + 256) * 3 + 2];
    #pragma unroll
    for (int off = 32; off >= 1; off >>= 1) {
        a0 += __shfl_xor(a0, off);
        a1 += __shfl_xor(a1, off);
        a2 += __shfl_xor(a2, off);
    }
    __shared__ float red[4][3];
    int wv = t >> 6, ln = t & 63;
    if (ln == 0) { red[wv][0] = a0; red[wv][1] = a1; red[wv][2] = a2; }
    __syncthreads();
    if (t < 3) {
        out[s * 3 + t] = red[0][t] + red[1][t] + red[2][t] + red[3][t] + b[t];
    }
}

// ---------------------------------------------------------------- launch

extern "C" void kernel_launch(void* const* d_in, const int* in_sizes, int n_in,
                              void* d_out, int out_size, void* d_ws, size_t ws_size,
                              hipStream_t stream) {
    const float* x        = (const float*)d_in[0];
    const int*   eidx     = (const int*)  d_in[1];
    const int*   tmask    = (const int*)  d_in[2];
    const float* lin1_W   = (const float*)d_in[3];
    const float* lin1_b   = (const float*)d_in[4];
    const float* convs_W  = (const float*)d_in[5];
    const float* att_dst  = (const float*)d_in[6];
    const float* att_src  = (const float*)d_in[7];
    const float* convs_b  = (const float*)d_in[8];
    const float* lin3_W   = (const float*)d_in[9];
    const float* lin3_b   = (const float*)d_in[10];
    float* out = (float*)d_out;

    char* ws = (char*)d_ws;
    size_t off = 0;
    auto alloc = [&](size_t bytes) -> void* {
        void* p = ws + off;
        off = (off + bytes + 255) & ~(size_t)255;
        return p;
    };
    _Float16* xh   = (_Float16*)alloc((size_t)N_PAD * KP1 * 2);
    _Float16* h    = (_Float16*)alloc((size_t)N_PAD * HID * 2);
    _Float16* hw   = (_Float16*)alloc((size_t)N_PAD * HID * 2);   // head-major [8][N][32]
    _Float16* w1t  = (_Float16*)alloc((size_t)HID * KP1 * 2);
    _Float16* wct  = (_Float16*)alloc((size_t)LAYERS * HID * HID * 2);
    float* sdst    = (float*)alloc((size_t)HEADS * N_NODES * 4);  // head-major
    float* ssrc    = (float*)alloc((size_t)HEADS * NS1 * 4);      // head-major + sentinel
    int*   counts  = (int*)  alloc((size_t)N_NODES * 4);
    int*   rowptr  = (int*)  alloc((size_t)(N_NODES + 1) * 4);
    int*   cursor  = (int*)  alloc((size_t)N_NODES * 4);
    u16*   col     = (u16*)  alloc((size_t)(EPAD + 32) * 2);
    ull*   bpart   = (ull*)  alloc((size_t)NB * BCAP * 8);
    int*   bcnt    = (int*)  alloc((size_t)NB * 4);
    int*   gcount  = (int*)  alloc((size_t)NBLK_P * NB * 4);
    int*   goff    = (int*)  alloc((size_t)NBLK_P * NB * 4);
    int*   bsum    = (int*)  alloc((size_t)NBLK_S * 4);
    int*   boff    = (int*)  alloc((size_t)NBLK_S * 4);

    const int* src = eidx;
    const int* tgt = eidx + E_EDGES;

    // CSR build
    hipMemsetAsync(counts, 0, (size_t)N_NODES * 4, stream);
    part_count_kernel<<<NBLK_P, 256, 0, stream>>>(tgt, gcount);
    part_scan_kernel<<<1, NBLK_P, 0, stream>>>(gcount, goff, bcnt);
    part_scatter_kernel<<<NBLK_P, 256, 0, stream>>>(src, tgt, goff, bpart);
    count_edges_kernel<<<NBLK_B, 256, 0, stream>>>(bpart, bcnt, counts);
    scan1_kernel<<<NBLK_S, 256, 0, stream>>>(counts, rowptr, bsum);
    scan2_kernel<<<1, 256, 0, stream>>>(bsum, boff, rowptr);
    scan3_kernel<<<NBLK_S, 256, 0, stream>>>(rowptr, boff, cursor);
    fill_edges_kernel<<<NBLK_B, 256, 0, stream>>>(bpart, bcnt, cursor, col);
    pad_edges_kernel<<<(N_NODES + 255) / 256, 256, 0, stream>>>(cursor, rowptr, col);

    // casts
    cast_x_kernel<<<(N_NODES * (KP1 / 8) + 255) / 256, 256, 0, stream>>>(x, xh);
    cast_w1_kernel<<<(HID * KP1 + 255) / 256, 256, 0, stream>>>(lin1_W, w1t);
    cast_wc_kernel<<<(LAYERS * HID * HID + 255) / 256, 256, 0, stream>>>(convs_W, wct);

    // lin1 (node-major output)
    gemm_mfma_kernel<<<dim3((N_NODES + 127) / 128, HID / 128), 256, 0, stream>>>(
        xh, w1t, lin1_b, h, N_NODES, KP1, 1, 0);

    for (int l = 0; l < LAYERS; l++) {
        // conv GEMM -> head-major hw
        gemm_mfma_kernel<<<dim3((N_NODES + 127) / 128, HID / 128), 256, 0, stream>>>(
            h, wct + (size_t)l * HID * HID, nullptr, hw, N_NODES, HID, 0, 1);
        score_kernel<<<512, 256, 0, stream>>>(
            hw, att_dst + (size_t)l * HEADS * OC, att_src + (size_t)l * HEADS * OC, sdst, ssrc);
        agg_kernel<<<NAGG, 256, 0, stream>>>(
            rowptr, col, sdst, ssrc, hw, convs_b + (size_t)l * HID, h);
    }

    head_kernel<<<BSAMP, 256, 0, stream>>>(h, tmask, lin3_W, lin3_b, out);
}